// Round 6
// baseline (311.752 us; speedup 1.0000x reference)
//
#include <hip/hip_runtime.h>
#include <hip/hip_bf16.h>
#include <stdint.h>

#define DMODEL 256
#define BATCH  16
#define MEL    2048
#define SRC    512
#define TB     16
#define SP2    2056   // P_lds row stride (bf16 units)

typedef __attribute__((ext_vector_type(8))) short bf16x8;
typedef __attribute__((ext_vector_type(4))) float f32x4;

__device__ inline short f2bf(float f) {
    union { float f; uint32_t u; } c{f};
    uint32_t u = c.u;
    u += 0x7FFFu + ((u >> 16) & 1u);   // RNE
    return (short)(u >> 16);
}

__device__ inline float bf2f(short s) {
    union { uint32_t u; float f; } c;
    c.u = ((uint32_t)(uint16_t)s) << 16;
    return c.f;
}

__device__ inline bf16x8 cvt8(const float* p) {
    const f32x4* q = reinterpret_cast<const f32x4*>(p);
    f32x4 a = q[0], b = q[1];
    bf16x8 r;
    r[0] = f2bf(a[0]); r[1] = f2bf(a[1]); r[2] = f2bf(a[2]); r[3] = f2bf(a[3]);
    r[4] = f2bf(b[0]); r[5] = f2bf(b[1]); r[6] = f2bf(b[2]); r[7] = f2bf(b[3]);
    return r;
}

// ---- convert Wq|Wk|Wv (each 256x256 f32) -> bf16, concatenated ----
__global__ __launch_bounds__(256)
void wconv_kernel(const float* __restrict__ Wq, const float* __restrict__ Wk,
                  const float* __restrict__ Wv, short* __restrict__ wb) {
    int i = blockIdx.x * 256 + threadIdx.x;
    int which = i >> 13;
    int off = (i & 8191) * 8;
    const float* src = which == 0 ? Wq : (which == 1 ? Wk : Wv);
    *reinterpret_cast<bf16x8*>(wb + which * 65536 + off) = cvt8(src + off);
}

// ---- q = text @ Wq^T. 128 thr (2 waves), 256 blocks, 32 rows/block.
//      LDS-staged vectorized stores. ----
__global__ __launch_bounds__(128)
void qproj_kernel(const float* __restrict__ text, const short* __restrict__ Wqb,
                  short* __restrict__ qbf) {
    __shared__ short qlds[32 * 264];   // 16.9 KB
    const int tid = threadIdx.x;
    const int lane = tid & 63, w = tid >> 6;
    const int lr = lane & 15, lk = lane >> 4;
    const int row0 = blockIdx.x * 32 + w * 16;

    bf16x8 afr[8];
    const float* arow = text + (size_t)(row0 + lr) * DMODEL + 8 * lk;
#pragma unroll
    for (int t = 0; t < 8; ++t) afr[t] = cvt8(arow + 32 * t);

    f32x4 acc[16];
#pragma unroll
    for (int n = 0; n < 16; ++n) {
        acc[n] = (f32x4){0.f, 0.f, 0.f, 0.f};
        const short* brow = Wqb + (size_t)(16 * n + lr) * DMODEL + 8 * lk;
#pragma unroll
        for (int t = 0; t < 8; ++t) {
            bf16x8 bfr = *reinterpret_cast<const bf16x8*>(brow + 32 * t);
            acc[n] = __builtin_amdgcn_mfma_f32_16x16x32_bf16(afr[t], bfr, acc[n], 0, 0, 0);
        }
    }
#pragma unroll
    for (int n = 0; n < 16; ++n)
#pragma unroll
        for (int r = 0; r < 4; ++r)
            qlds[(16 * w + 4 * lk + r) * 264 + 16 * n + lr] = f2bf(acc[n][r]);
    __syncthreads();

    short* gdst = qbf + (size_t)blockIdx.x * 32 * DMODEL;   // contiguous 32x256 tile
#pragma unroll
    for (int c = 0; c < 8; ++c) {
        int idx = c * 128 + tid;                            // 0..1023, 8 shorts each
        *reinterpret_cast<bf16x8*>(gdst + idx * 8) =
            *reinterpret_cast<const bf16x8*>(&qlds[(idx >> 5) * 264 + (idx & 31) * 8]);
    }
}

// ---- fused K/V projection with LDS-staged vectorized stores ----
// grid (MEL/64, BATCH), 256 threads. mlds reused: mel(64x264) -> k(64x264) -> vt(256x66)
__global__ __launch_bounds__(256)
void kvproj_kernel(const float* __restrict__ mel, const short* __restrict__ Wkb,
                   const short* __restrict__ Wvb, short* __restrict__ kbf,
                   short* __restrict__ vt) {
    __shared__ short mlds[16896];   // 33,792 B (64*264 == 256*66 == 16896)

    const int tid = threadIdx.x;
    const int b = blockIdx.y, mr0 = blockIdx.x * 64;

    const float* gsrc = mel + (size_t)(b * MEL + mr0) * DMODEL;
#pragma unroll
    for (int i = 0; i < 8; ++i) {
        int row = (tid >> 5) + 8 * i, col = (tid & 31) * 8;
        *reinterpret_cast<bf16x8*>(&mlds[row * 264 + col]) = cvt8(gsrc + row * DMODEL + col);
    }
    __syncthreads();

    const int lane = tid & 63, w = tid >> 6;
    const int lr = lane & 15, lk = lane >> 4;

    // k accs: wave w -> mel rows [16w,16w+16), all 256 out cols
    bf16x8 afr[8];
#pragma unroll
    for (int t = 0; t < 8; ++t)
        afr[t] = *reinterpret_cast<const bf16x8*>(&mlds[(16 * w + lr) * 264 + 8 * lk + 32 * t]);
    f32x4 kacc[16];
#pragma unroll
    for (int n = 0; n < 16; ++n) {
        kacc[n] = (f32x4){0.f, 0.f, 0.f, 0.f};
        const short* brow = Wkb + (size_t)(16 * n + lr) * DMODEL + 8 * lk;
#pragma unroll
        for (int t = 0; t < 8; ++t) {
            bf16x8 bfr = *reinterpret_cast<const bf16x8*>(brow + 32 * t);
            kacc[n] = __builtin_amdgcn_mfma_f32_16x16x32_bf16(afr[t], bfr, kacc[n], 0, 0, 0);
        }
    }

    // v accs: wave w -> vt rows [64w,64w+64), cols = this block's 64 mel rows
    f32x4 vacc[4][4];
#pragma unroll
    for (int m = 0; m < 4; ++m) {
        bf16x8 a2[8];
        const short* arow2 = Wvb + (size_t)(64 * w + 16 * m + lr) * DMODEL + 8 * lk;
#pragma unroll
        for (int t = 0; t < 8; ++t)
            a2[t] = *reinterpret_cast<const bf16x8*>(arow2 + 32 * t);
#pragma unroll
        for (int n = 0; n < 4; ++n) {
            vacc[m][n] = (f32x4){0.f, 0.f, 0.f, 0.f};
#pragma unroll
            for (int t = 0; t < 8; ++t) {
                bf16x8 bfr = *reinterpret_cast<const bf16x8*>(
                    &mlds[(16 * n + lr) * 264 + 8 * lk + 32 * t]);
                vacc[m][n] = __builtin_amdgcn_mfma_f32_16x16x32_bf16(a2[t], bfr, vacc[m][n], 0, 0, 0);
            }
        }
    }
    __syncthreads();   // all reads of mel in mlds done

    // stage + store k (64x256 tile is contiguous in kbf)
#pragma unroll
    for (int n = 0; n < 16; ++n)
#pragma unroll
        for (int r = 0; r < 4; ++r)
            mlds[(16 * w + 4 * lk + r) * 264 + 16 * n + lr] = f2bf(kacc[n][r]);
    __syncthreads();
    {
        short* gdst = kbf + (size_t)(b * MEL + mr0) * DMODEL;
#pragma unroll
        for (int c = 0; c < 8; ++c) {
            int idx = c * 256 + tid;   // 0..2047, 8 shorts each
            *reinterpret_cast<bf16x8*>(gdst + idx * 8) =
                *reinterpret_cast<const bf16x8*>(&mlds[(idx >> 5) * 264 + (idx & 31) * 8]);
        }
    }
    __syncthreads();

    // stage + store vt (256 rows x 64 cols, global row stride MEL)
#pragma unroll
    for (int m = 0; m < 4; ++m)
#pragma unroll
        for (int n = 0; n < 4; ++n)
#pragma unroll
            for (int r = 0; r < 4; ++r)
                mlds[(64 * w + 16 * m + 4 * lk + r) * 66 + 16 * n + lr] = f2bf(vacc[m][n][r]);
    __syncthreads();
    {
#pragma unroll
        for (int c = 0; c < 8; ++c) {
            int idx = c * 256 + tid;              // 0..2047
            int row = idx >> 3, col = (idx & 7) * 8;
            *reinterpret_cast<bf16x8*>(vt + (size_t)(b * DMODEL + row) * MEL + mr0 + col) =
                *reinterpret_cast<const bf16x8*>(&mlds[row * 66 + col]);
        }
    }
}

// ---- fused attention: XCD-swizzled 1D grid; register S; P bf16 in LDS;
//      vectorized attn write; fused LN ----
__global__ __launch_bounds__(512, 4)
void attn_kernel(const short* __restrict__ qbf, const short* __restrict__ kbf,
                 const short* __restrict__ vt,
                 const int* __restrict__ mel_mask, const int* __restrict__ src_mask,
                 const float* __restrict__ gamma, const float* __restrict__ beta,
                 float* __restrict__ out, float* __restrict__ attn_out) {
    __shared__ short P[TB * SP2];     // 65,792 B
    __shared__ float red[2][TB][8];

    const int tid = threadIdx.x;
    const int lane = tid & 63, w = tid >> 6;
    const int lr = lane & 15, lk = lane >> 4;

    // XCD-aware decode: XCD x owns batches {2x, 2x+1} (64 blocks = 2 batches/XCD)
    const int bid = blockIdx.x;
    const int idx = bid >> 3;
    const int b = 2 * (bid & 7) + (idx >> 5);
    const int t_base = (idx & 31) * TB;
    const int c0 = w * 256;

    bf16x8 qfr[8];
    const short* qrow = qbf + (size_t)(b * SRC + t_base + lr) * DMODEL + 8 * lk;
#pragma unroll
    for (int t = 0; t < 8; ++t)
        qfr[t] = *reinterpret_cast<const bf16x8*>(qrow + 32 * t);

    // ---- Phase 1: S = qk^T/16 + mel mask ----
    f32x4 acc[16];
#pragma unroll
    for (int tile = 0; tile < 16; ++tile) {
        f32x4 a = {0.f, 0.f, 0.f, 0.f};
        const short* krow = kbf + (size_t)(b * MEL + c0 + tile * 16 + lr) * DMODEL + 8 * lk;
#pragma unroll
        for (int t = 0; t < 8; ++t) {
            bf16x8 kfr = *reinterpret_cast<const bf16x8*>(krow + 32 * t);
            a = __builtin_amdgcn_mfma_f32_16x16x32_bf16(qfr[t], kfr, a, 0, 0, 0);
        }
        const bool masked = mel_mask[b * MEL + c0 + tile * 16 + lr] != 0;
#pragma unroll
        for (int r = 0; r < 4; ++r)
            acc[tile][r] = masked ? -1e30f : a[r] * 0.0625f;
    }

    // ---- Phase 2: softmax ----
    float mr[4] = {-3.0e38f, -3.0e38f, -3.0e38f, -3.0e38f};
#pragma unroll
    for (int tile = 0; tile < 16; ++tile)
#pragma unroll
        for (int r = 0; r < 4; ++r) mr[r] = fmaxf(mr[r], acc[tile][r]);
#pragma unroll
    for (int off = 8; off; off >>= 1)
#pragma unroll
        for (int r = 0; r < 4; ++r) mr[r] = fmaxf(mr[r], __shfl_xor(mr[r], off));
    if (lr == 0) {
#pragma unroll
        for (int r = 0; r < 4; ++r) red[0][4 * lk + r][w] = mr[r];
    }
    __syncthreads();
    float M[4];
#pragma unroll
    for (int r = 0; r < 4; ++r) {
        float m = red[0][4 * lk + r][0];
#pragma unroll
        for (int j = 1; j < 8; ++j) m = fmaxf(m, red[0][4 * lk + r][j]);
        M[r] = m;
    }
    float sr[4] = {0.f, 0.f, 0.f, 0.f};
#pragma unroll
    for (int tile = 0; tile < 16; ++tile)
#pragma unroll
        for (int r = 0; r < 4; ++r) {
            float e = __expf(acc[tile][r] - M[r]);
            acc[tile][r] = e;
            sr[r] += e;
        }
#pragma unroll
    for (int off = 8; off; off >>= 1)
#pragma unroll
        for (int r = 0; r < 4; ++r) sr[r] += __shfl_xor(sr[r], off);
    if (lr == 0) {
#pragma unroll
        for (int r = 0; r < 4; ++r) red[1][4 * lk + r][w] = sr[r];
    }
    __syncthreads();
    float inv[4];
#pragma unroll
    for (int r = 0; r < 4; ++r) {
        float s = red[1][4 * lk + r][0];
#pragma unroll
        for (int j = 1; j < 8; ++j) s += red[1][4 * lk + r][j];
        inv[r] = src_mask[b * SRC + t_base + 4 * lk + r] ? 0.f : 1.f / s;
    }

    // ---- Phase 2b: P (bf16) to LDS only ----
#pragma unroll
    for (int tile = 0; tile < 16; ++tile) {
        const int col = c0 + tile * 16 + lr;
#pragma unroll
        for (int r = 0; r < 4; ++r)
            P[(4 * lk + r) * SP2 + col] = f2bf(acc[tile][r] * inv[r]);
    }
    __syncthreads();

    // ---- Phase 2c: vectorized attn write from P (bf16-rounded, within tol) ----
    {
        float* abase = attn_out + (size_t)(b * SRC + t_base) * MEL;
        const int half = tid >> 8;            // 0/1
        const int c8 = (tid & 255) * 8;
#pragma unroll
        for (int it = 0; it < 8; ++it) {
            int row = 2 * it + half;
            bf16x8 p8 = *reinterpret_cast<const bf16x8*>(&P[row * SP2 + c8]);
            f32x4 lo = { bf2f(p8[0]), bf2f(p8[1]), bf2f(p8[2]), bf2f(p8[3]) };
            f32x4 hi = { bf2f(p8[4]), bf2f(p8[5]), bf2f(p8[6]), bf2f(p8[7]) };
            f32x4* g = reinterpret_cast<f32x4*>(abase + (size_t)row * MEL + c8);
            g[0] = lo;
            g[1] = hi;
        }
    }

    // ---- Phase 3: PV. wave w -> out cols [32w, 32w+32) ----
    f32x4 pacc[2];
    pacc[0] = (f32x4){0.f, 0.f, 0.f, 0.f};
    pacc[1] = (f32x4){0.f, 0.f, 0.f, 0.f};
    for (int ks = 0; ks < MEL / 32; ++ks) {
        bf16x8 pa = *reinterpret_cast<const bf16x8*>(&P[lr * SP2 + 32 * ks + 8 * lk]);
#pragma unroll
        for (int n = 0; n < 2; ++n) {
            const short* vrow = vt + (size_t)(b * DMODEL + w * 32 + n * 16 + lr) * MEL +
                                32 * ks + 8 * lk;
            bf16x8 vfr = *reinterpret_cast<const bf16x8*>(vrow);
            pacc[n] = __builtin_amdgcn_mfma_f32_16x16x32_bf16(pa, vfr, pacc[n], 0, 0, 0);
        }
    }
    __syncthreads();

    // ---- Phase 4: LN ----
    float* O = reinterpret_cast<float*>(P);
#pragma unroll
    for (int n = 0; n < 2; ++n)
#pragma unroll
        for (int r = 0; r < 4; ++r)
            O[(4 * lk + r) * 264 + w * 32 + n * 16 + lr] = pacc[n][r];
    __syncthreads();

    {
        const int row = tid >> 5, l = tid & 31;
        const float* orow = O + row * 264;
        float s1 = 0.f;
#pragma unroll
        for (int j = 0; j < 8; ++j) s1 += orow[l + 32 * j];
#pragma unroll
        for (int off = 16; off; off >>= 1) s1 += __shfl_xor(s1, off);
        const float mu = s1 * (1.f / DMODEL);
        float s2 = 0.f;
#pragma unroll
        for (int j = 0; j < 8; ++j) {
            float d = orow[l + 32 * j] - mu;
            s2 += d * d;
        }
#pragma unroll
        for (int off = 16; off; off >>= 1) s2 += __shfl_xor(s2, off);
        const float rsig = rsqrtf(s2 * (1.f / DMODEL) + 1e-5f);
        float* g = out + (size_t)(b * SRC + t_base + row) * DMODEL;
#pragma unroll
        for (int j = 0; j < 8; ++j) {
            int i = l + 32 * j;
            g[i] = (orow[i] - mu) * rsig * gamma[i] + beta[i];
        }
    }
}

extern "C" void kernel_launch(void* const* d_in, const int* in_sizes, int n_in,
                              void* d_out, int out_size, void* d_ws, size_t ws_size,
                              hipStream_t stream) {
    const float* mel      = (const float*)d_in[0];
    const float* text     = (const float*)d_in[1];
    const int*   mel_mask = (const int*)d_in[2];
    const int*   src_mask = (const int*)d_in[3];
    const float* Wq       = (const float*)d_in[4];
    const float* Wk       = (const float*)d_in[5];
    const float* Wv       = (const float*)d_in[6];
    const float* gamma    = (const float*)d_in[7];
    const float* beta     = (const float*)d_in[8];

    float* out      = (float*)d_out;
    float* attn_out = out + (size_t)BATCH * SRC * DMODEL;

    short* wb  = (short*)d_ws;
    short* Wqb = wb;
    short* Wkb = wb + 65536;
    short* Wvb = wb + 131072;
    short* qbf = wb + 3 * 65536;
    short* kbf = qbf + (size_t)BATCH * SRC * DMODEL;
    short* vt  = kbf + (size_t)BATCH * MEL * DMODEL;

    wconv_kernel<<<96, 256, 0, stream>>>(Wq, Wk, Wv, wb);
    qproj_kernel<<<BATCH * SRC / 32, 128, 0, stream>>>(text, Wqb, qbf);
    kvproj_kernel<<<dim3(MEL / 64, BATCH), 256, 0, stream>>>(mel, Wkb, Wvb, kbf, vt);
    attn_kernel<<<SRC / TB * BATCH, 512, 0, stream>>>(
        qbf, kbf, vt, mel_mask, src_mask, gamma, beta, out, attn_out);
}